// Round 1
// baseline (2077.331 us; speedup 1.0000x reference)
//
#include <hip/hip_runtime.h>
#include <cmath>

#define BB 16
#define NN 4096
#define DD 1024
#define HH 512
#define OO 4096
#define KSEL 200
#define NT (BB * NN)   // 65536 tokens

#define KC 16
#define TILE 128
#define LDP (TILE + 4)  // 132: row stride keeps float4 alignment (132*4 % 16 == 0)

// ---------------------------------------------------------------------------
// Kernel 1: scores.  a = x @ W1^T + b1; h = gelu_exact(a); partial = h @ W2
// Each block: 128 tokens x 128 h, K-loop over D.  H split into 4 tiles ->
// deterministic partials[4][NT] summed later in fixed order (no atomics).
// ---------------------------------------------------------------------------
__global__ __launch_bounds__(256) void score_kernel(
    const float* __restrict__ x,      // [NT, DD]
    const float* __restrict__ W1,     // [HH, DD]
    const float* __restrict__ b1,     // [HH]
    const float* __restrict__ W2,     // [HH]
    float* __restrict__ partials)     // [HH/TILE = 4][NT]
{
    __shared__ float As[KC][LDP];
    __shared__ float Bs[KC][LDP];

    const int tid = threadIdx.x;
    const int t0 = blockIdx.x * TILE;
    const int h0 = blockIdx.y * TILE;
    const int tx = tid & 15;          // h-group 0..15
    const int ty = tid >> 4;          // token-group 0..15
    const int lt = tid >> 2;          // loader row 0..63
    const int lq = tid & 3;           // loader k-quad 0..3

    const float* Arow0 = x + (size_t)(t0 + lt) * DD;
    const float* Arow1 = x + (size_t)(t0 + lt + 64) * DD;
    const float* Brow0 = W1 + (size_t)(h0 + lt) * DD;
    const float* Brow1 = W1 + (size_t)(h0 + lt + 64) * DD;

    float acc[8][8];
#pragma unroll
    for (int i = 0; i < 8; ++i)
#pragma unroll
        for (int j = 0; j < 8; ++j) acc[i][j] = 0.0f;

    for (int kc = 0; kc < DD; kc += KC) {
        float4 a0 = *(const float4*)(Arow0 + kc + lq * 4);
        float4 a1 = *(const float4*)(Arow1 + kc + lq * 4);
        float4 w0 = *(const float4*)(Brow0 + kc + lq * 4);
        float4 w1 = *(const float4*)(Brow1 + kc + lq * 4);
        __syncthreads();
        As[lq * 4 + 0][lt] = a0.x; As[lq * 4 + 1][lt] = a0.y;
        As[lq * 4 + 2][lt] = a0.z; As[lq * 4 + 3][lt] = a0.w;
        As[lq * 4 + 0][lt + 64] = a1.x; As[lq * 4 + 1][lt + 64] = a1.y;
        As[lq * 4 + 2][lt + 64] = a1.z; As[lq * 4 + 3][lt + 64] = a1.w;
        Bs[lq * 4 + 0][lt] = w0.x; Bs[lq * 4 + 1][lt] = w0.y;
        Bs[lq * 4 + 2][lt] = w0.z; Bs[lq * 4 + 3][lt] = w0.w;
        Bs[lq * 4 + 0][lt + 64] = w1.x; Bs[lq * 4 + 1][lt + 64] = w1.y;
        Bs[lq * 4 + 2][lt + 64] = w1.z; Bs[lq * 4 + 3][lt + 64] = w1.w;
        __syncthreads();
#pragma unroll
        for (int kk = 0; kk < KC; ++kk) {
            float ra[8], rb[8];
            *(float4*)&ra[0] = *(const float4*)&As[kk][ty * 8];
            *(float4*)&ra[4] = *(const float4*)&As[kk][ty * 8 + 4];
            *(float4*)&rb[0] = *(const float4*)&Bs[kk][tx * 8];
            *(float4*)&rb[4] = *(const float4*)&Bs[kk][tx * 8 + 4];
#pragma unroll
            for (int i = 0; i < 8; ++i)
#pragma unroll
                for (int j = 0; j < 8; ++j)
                    acc[i][j] = fmaf(ra[i], rb[j], acc[i][j]);
        }
    }

    // Epilogue: gelu + W2-weighted sum over this h-tile, reduce across tx.
    float s[8];
#pragma unroll
    for (int i = 0; i < 8; ++i) s[i] = 0.0f;
#pragma unroll
    for (int j = 0; j < 8; ++j) {
        const int h = h0 + tx * 8 + j;
        const float bias = b1[h];
        const float w2v = W2[h];
#pragma unroll
        for (int i = 0; i < 8; ++i) {
            float u = acc[i][j] + bias;
            float g = 0.5f * u * (1.0f + erff(u * 0.70710678118654752440f));
            s[i] = fmaf(g, w2v, s[i]);
        }
    }
    // deterministic fixed-order tree over the 16 tx lanes (same wave: 16|64)
#pragma unroll
    for (int i = 0; i < 8; ++i) {
#pragma unroll
        for (int off = 8; off > 0; off >>= 1)
            s[i] += __shfl_down(s[i], off, 16);
    }
    if (tx == 0) {
#pragma unroll
        for (int i = 0; i < 8; ++i)
            partials[(size_t)blockIdx.y * NT + t0 + ty * 8 + i] = s[i];
    }
}

// ---------------------------------------------------------------------------
// Kernel 2: per-batch top-200, sorted descending, ties -> lower index.
// One block per batch; partials summed in fixed order -> deterministic.
// ---------------------------------------------------------------------------
__global__ __launch_bounds__(256) void topk_kernel(
    const float* __restrict__ partials,  // [4][NT]
    int* __restrict__ topk)              // [BB, KSEL]
{
    __shared__ float ls[NN];
    __shared__ float rv[4];
    __shared__ int ri[4];
    const int b = blockIdx.x;
    const int tid = threadIdx.x;

    for (int i = tid; i < NN; i += 256) {
        const int t = b * NN + i;
        float v = partials[t];
        v += partials[NT + t];
        v += partials[2 * NT + t];
        v += partials[3 * NT + t];
        ls[i] = v;
    }
    __syncthreads();

    for (int k = 0; k < KSEL; ++k) {
        float bv = -INFINITY;
        int bi = 0x7fffffff;
        for (int i = tid; i < NN; i += 256) {  // increasing i + strict > => lowest index on tie
            float v = ls[i];
            if (v > bv) { bv = v; bi = i; }
        }
#pragma unroll
        for (int off = 32; off > 0; off >>= 1) {
            float ov = __shfl_down(bv, off, 64);
            int oi = __shfl_down(bi, off, 64);
            if (ov > bv || (ov == bv && oi < bi)) { bv = ov; bi = oi; }
        }
        const int lane = tid & 63, w = tid >> 6;
        if (lane == 0) { rv[w] = bv; ri[w] = bi; }
        __syncthreads();
        if (tid == 0) {
            float xv = rv[0]; int xi = ri[0];
#pragma unroll
            for (int g = 1; g < 4; ++g)
                if (rv[g] > xv || (rv[g] == xv && ri[g] < xi)) { xv = rv[g]; xi = ri[g]; }
            topk[b * KSEL + k] = xi;
            ls[xi] = -INFINITY;
        }
        __syncthreads();
    }
}

// ---------------------------------------------------------------------------
// Kernel 3: gathered projection  out[r,o] = x[row(r),:] . Wp[o,:] + bp[o]
// M = 3200 flat rows (r -> batch r/200, token topk[r]).
// ---------------------------------------------------------------------------
__global__ __launch_bounds__(256) void proj_kernel(
    const float* __restrict__ x,     // [NT, DD]
    const int* __restrict__ topk,    // [BB*KSEL]
    const float* __restrict__ Wp,    // [OO, DD]
    const float* __restrict__ bp,    // [OO]
    float* __restrict__ out)         // [BB*KSEL, OO]
{
    __shared__ float As[KC][LDP];
    __shared__ float Bs[KC][LDP];
    __shared__ int rowbase[TILE];

    const int tid = threadIdx.x;
    const int r0 = blockIdx.x * TILE;
    const int o0 = blockIdx.y * TILE;
    const int tx = tid & 15;
    const int ty = tid >> 4;
    const int lt = tid >> 2;
    const int lq = tid & 3;

    if (tid < TILE) {
        const int r = r0 + tid;
        const int bat = r / KSEL;
        rowbase[tid] = bat * NN + topk[r];
    }
    __syncthreads();
    const int ra0 = rowbase[lt];
    const int ra1 = rowbase[lt + 64];

    const float* Arow0 = x + (size_t)ra0 * DD;
    const float* Arow1 = x + (size_t)ra1 * DD;
    const float* Brow0 = Wp + (size_t)(o0 + lt) * DD;
    const float* Brow1 = Wp + (size_t)(o0 + lt + 64) * DD;

    float acc[8][8];
#pragma unroll
    for (int i = 0; i < 8; ++i)
#pragma unroll
        for (int j = 0; j < 8; ++j) acc[i][j] = 0.0f;

    for (int kc = 0; kc < DD; kc += KC) {
        float4 a0 = *(const float4*)(Arow0 + kc + lq * 4);
        float4 a1 = *(const float4*)(Arow1 + kc + lq * 4);
        float4 w0 = *(const float4*)(Brow0 + kc + lq * 4);
        float4 w1 = *(const float4*)(Brow1 + kc + lq * 4);
        __syncthreads();
        As[lq * 4 + 0][lt] = a0.x; As[lq * 4 + 1][lt] = a0.y;
        As[lq * 4 + 2][lt] = a0.z; As[lq * 4 + 3][lt] = a0.w;
        As[lq * 4 + 0][lt + 64] = a1.x; As[lq * 4 + 1][lt + 64] = a1.y;
        As[lq * 4 + 2][lt + 64] = a1.z; As[lq * 4 + 3][lt + 64] = a1.w;
        Bs[lq * 4 + 0][lt] = w0.x; Bs[lq * 4 + 1][lt] = w0.y;
        Bs[lq * 4 + 2][lt] = w0.z; Bs[lq * 4 + 3][lt] = w0.w;
        Bs[lq * 4 + 0][lt + 64] = w1.x; Bs[lq * 4 + 1][lt + 64] = w1.y;
        Bs[lq * 4 + 2][lt + 64] = w1.z; Bs[lq * 4 + 3][lt + 64] = w1.w;
        __syncthreads();
#pragma unroll
        for (int kk = 0; kk < KC; ++kk) {
            float ra[8], rb[8];
            *(float4*)&ra[0] = *(const float4*)&As[kk][ty * 8];
            *(float4*)&ra[4] = *(const float4*)&As[kk][ty * 8 + 4];
            *(float4*)&rb[0] = *(const float4*)&Bs[kk][tx * 8];
            *(float4*)&rb[4] = *(const float4*)&Bs[kk][tx * 8 + 4];
#pragma unroll
            for (int i = 0; i < 8; ++i)
#pragma unroll
                for (int j = 0; j < 8; ++j)
                    acc[i][j] = fmaf(ra[i], rb[j], acc[i][j]);
        }
    }

    const float4 bp0 = *(const float4*)(bp + o0 + tx * 8);
    const float4 bp1 = *(const float4*)(bp + o0 + tx * 8 + 4);
#pragma unroll
    for (int i = 0; i < 8; ++i) {
        const size_t orow = (size_t)(r0 + ty * 8 + i) * OO + o0 + tx * 8;
        float4 v0, v1;
        v0.x = acc[i][0] + bp0.x; v0.y = acc[i][1] + bp0.y;
        v0.z = acc[i][2] + bp0.z; v0.w = acc[i][3] + bp0.w;
        v1.x = acc[i][4] + bp1.x; v1.y = acc[i][5] + bp1.y;
        v1.z = acc[i][6] + bp1.z; v1.w = acc[i][7] + bp1.w;
        *(float4*)(out + orow) = v0;
        *(float4*)(out + orow + 4) = v1;
    }
}

// ---------------------------------------------------------------------------
extern "C" void kernel_launch(void* const* d_in, const int* in_sizes, int n_in,
                              void* d_out, int out_size, void* d_ws, size_t ws_size,
                              hipStream_t stream) {
    const float* x  = (const float*)d_in[0];
    const float* W1 = (const float*)d_in[1];
    const float* b1 = (const float*)d_in[2];
    const float* W2 = (const float*)d_in[3];
    // d_in[4] = b2: uniform shift of all scores -> does not affect top-k; scores not output.
    const float* Wp = (const float*)d_in[5];
    const float* bp = (const float*)d_in[6];
    float* out = (float*)d_out;

    float* partials = (float*)d_ws;                                   // 4 * NT floats = 1 MB
    int* topk = (int*)((char*)d_ws + (size_t)4 * NT * sizeof(float)); // 3200 ints

    dim3 g1(NT / TILE, HH / TILE);   // (512, 4)
    score_kernel<<<g1, 256, 0, stream>>>(x, W1, b1, W2, partials);

    topk_kernel<<<dim3(BB), 256, 0, stream>>>(partials, topk);

    dim3 g3((BB * KSEL) / TILE, OO / TILE);  // (25, 32)
    proj_kernel<<<g3, 256, 0, stream>>>(x, topk, Wp, bp, out);
}

// Round 2
// 1197.739 us; speedup vs baseline: 1.7344x; 1.7344x over previous
//
#include <hip/hip_runtime.h>
#include <cmath>

#define BB 16
#define NN 4096
#define DD 1024
#define HH 512
#define OO 4096
#define KSEL 200
#define NCAND 256
#define NT (BB * NN)          // 65536
#define NSLOT (BB * NCAND)    // 4096

typedef __bf16 bf16x8 __attribute__((ext_vector_type(8)));
typedef float floatx4 __attribute__((ext_vector_type(4)));

#define BKA 32      // K-chunk (elements) for MFMA kernels
#define LDSA 40     // LDS row stride in ushorts (80 B = 32 elems + 8 pad) -> <=2-way bank alias

__device__ __forceinline__ unsigned short f2b(float f) {
    union { float f; unsigned u; } v; v.f = f;
    unsigned r = v.u + 0x7fffu + ((v.u >> 16) & 1u);   // RNE
    return (unsigned short)(r >> 16);
}
__device__ __forceinline__ unsigned pk2(float lo, float hi) {
    return (unsigned)f2b(lo) | ((unsigned)f2b(hi) << 16);
}

// ---------------------------------------------------------------------------
// fp32 -> bf16 converter (W1, Wp), 8 elems/thread
// ---------------------------------------------------------------------------
__global__ __launch_bounds__(256) void convert_bf16(
    const float* __restrict__ src, unsigned short* __restrict__ dst, int n8)
{
    int i = blockIdx.x * 256 + threadIdx.x;
    if (i >= n8) return;
    float4 a = ((const float4*)src)[2 * i];
    float4 b = ((const float4*)src)[2 * i + 1];
    uint4 o = make_uint4(pk2(a.x, a.y), pk2(a.z, a.w), pk2(b.x, b.y), pk2(b.z, b.w));
    ((uint4*)dst)[i] = o;
}

// ---------------------------------------------------------------------------
// Approx scores via bf16 MFMA: partials[4][NT] (h-tiles of 128, summed later).
// Block: 128 tokens x 128 h.  A: fp32 x converted in staging; B: W1b (bf16).
// grid = (HH/128 = 4, NT/128 = 512): x fastest -> 4 h-blocks share token tile.
// ---------------------------------------------------------------------------
__global__ __launch_bounds__(256) void score_mfma(
    const float* __restrict__ x, const unsigned short* __restrict__ W1b,
    const float* __restrict__ b1, const float* __restrict__ W2,
    float* __restrict__ partials)
{
    __shared__ __align__(16) unsigned short As[128 * LDSA];
    __shared__ __align__(16) unsigned short Bs[128 * LDSA];
    __shared__ float red[2][128];

    const int tid = threadIdx.x;
    const int h0 = blockIdx.x * 128;
    const int t0 = blockIdx.y * 128;
    const int lane = tid & 63;
    const int w = tid >> 6;
    const int wr = w & 1, wc = w >> 1;
    const int l15 = lane & 15, q = lane >> 4;
    const int sr = tid >> 1;      // staging row 0..127
    const int sc = tid & 1;       // staging half (16 elems)

    const float* xrow = x + (size_t)(t0 + sr) * DD + sc * 16;
    const unsigned short* wrow = W1b + (size_t)(h0 + sr) * DD + sc * 16;

    floatx4 acc[4][4];
#pragma unroll
    for (int mi = 0; mi < 4; ++mi)
#pragma unroll
        for (int ni = 0; ni < 4; ++ni) acc[mi][ni] = (floatx4){0.f, 0.f, 0.f, 0.f};

    for (int kc = 0; kc < DD; kc += BKA) {
        float4 a0 = *(const float4*)(xrow + kc);
        float4 a1 = *(const float4*)(xrow + kc + 4);
        float4 a2 = *(const float4*)(xrow + kc + 8);
        float4 a3 = *(const float4*)(xrow + kc + 12);
        uint4 bv0 = *(const uint4*)(wrow + kc);
        uint4 bv1 = *(const uint4*)(wrow + kc + 8);
        __syncthreads();   // previous tile's compute done
        uint4 ua0 = make_uint4(pk2(a0.x, a0.y), pk2(a0.z, a0.w), pk2(a1.x, a1.y), pk2(a1.z, a1.w));
        uint4 ua1 = make_uint4(pk2(a2.x, a2.y), pk2(a2.z, a2.w), pk2(a3.x, a3.y), pk2(a3.z, a3.w));
        *(uint4*)&As[sr * LDSA + sc * 16] = ua0;
        *(uint4*)&As[sr * LDSA + sc * 16 + 8] = ua1;
        *(uint4*)&Bs[sr * LDSA + sc * 16] = bv0;
        *(uint4*)&Bs[sr * LDSA + sc * 16 + 8] = bv1;
        __syncthreads();
        bf16x8 af[4], bf[4];
#pragma unroll
        for (int mi = 0; mi < 4; ++mi)
            af[mi] = *(const bf16x8*)&As[(wr * 64 + mi * 16 + l15) * LDSA + q * 8];
#pragma unroll
        for (int ni = 0; ni < 4; ++ni)
            bf[ni] = *(const bf16x8*)&Bs[(wc * 64 + ni * 16 + l15) * LDSA + q * 8];
#pragma unroll
        for (int mi = 0; mi < 4; ++mi)
#pragma unroll
            for (int ni = 0; ni < 4; ++ni)
                acc[mi][ni] = __builtin_amdgcn_mfma_f32_16x16x32_bf16(af[mi], bf[ni], acc[mi][ni], 0, 0, 0);
    }

    // epilogue: gelu + W2-dot over this block's 128 h, reduce cols -> tokens
    float s[4][4];
#pragma unroll
    for (int mi = 0; mi < 4; ++mi)
#pragma unroll
        for (int r = 0; r < 4; ++r) s[mi][r] = 0.f;
#pragma unroll
    for (int ni = 0; ni < 4; ++ni) {
        const int n = h0 + wc * 64 + ni * 16 + l15;
        const float bias = b1[n];
        const float w2v = W2[n];
#pragma unroll
        for (int mi = 0; mi < 4; ++mi)
#pragma unroll
            for (int r = 0; r < 4; ++r) {
                float u = acc[mi][ni][r] + bias;
                float g = 0.5f * u * (1.0f + erff(u * 0.70710678118654752440f));
                s[mi][r] = fmaf(g, w2v, s[mi][r]);
            }
    }
#pragma unroll
    for (int mi = 0; mi < 4; ++mi)
#pragma unroll
        for (int r = 0; r < 4; ++r) {
#pragma unroll
            for (int off = 1; off < 16; off <<= 1)
                s[mi][r] += __shfl_xor(s[mi][r], off, 64);
        }
    if (l15 == 0) {
#pragma unroll
        for (int mi = 0; mi < 4; ++mi)
#pragma unroll
            for (int r = 0; r < 4; ++r)
                red[wc][wr * 64 + mi * 16 + q * 4 + r] = s[mi][r];
    }
    __syncthreads();
    if (tid < 128)
        partials[(size_t)blockIdx.x * NT + t0 + tid] = red[0][tid] + red[1][tid];
}

// ---------------------------------------------------------------------------
// Per-batch candidate select: radix-select 256th-largest approx score,
// compact all > T + equal-T in ascending index.  Deterministic SET.
// ---------------------------------------------------------------------------
__global__ __launch_bounds__(256) void cand_select(
    const float* __restrict__ partials, int* __restrict__ cand)
{
    __shared__ unsigned uk[NN];
    __shared__ int hist[256];
    __shared__ int eq[64];
    __shared__ int sh_pref, sh_rk, sh_cntgt, sh_eqcnt;
    const int b = blockIdx.x, tid = threadIdx.x;

    for (int i = tid; i < NN; i += 256) {
        const int t = b * NN + i;
        float v = partials[t] + partials[NT + t] + partials[2 * NT + t] + partials[3 * NT + t];
        union { float f; unsigned u; } c; c.f = v;
        uk[i] = (c.u & 0x80000000u) ? ~c.u : (c.u | 0x80000000u);
    }
    if (tid == 0) { sh_pref = 0; sh_rk = NCAND; }
    __syncthreads();

    for (int sh = 24; sh >= 0; sh -= 8) {
        hist[tid] = 0;
        __syncthreads();
        const unsigned pref = (unsigned)sh_pref;
        for (int i = tid; i < NN; i += 256) {
            unsigned k = uk[i];
            bool match = (sh == 24) || (((k ^ pref) >> (sh + 8)) == 0);
            if (match) atomicAdd(&hist[(k >> sh) & 255], 1);
        }
        __syncthreads();
        if (tid == 0) {
            int rk = sh_rk, cum = 0;
            for (int bin = 255; bin >= 0; --bin) {
                int c = hist[bin];
                if (cum + c >= rk) { sh_pref = (int)(pref | ((unsigned)bin << sh)); sh_rk = rk - cum; break; }
                cum += c;
            }
        }
        __syncthreads();
    }
    const unsigned T = (unsigned)sh_pref;
    if (tid == 0) { sh_cntgt = 0; sh_eqcnt = 0; }
    cand[b * NCAND + tid] = 0;   // safe default (overwritten below)
    __syncthreads();
    for (int i = tid; i < NN; i += 256) {
        unsigned k = uk[i];
        if (k > T) {
            int p = atomicAdd(&sh_cntgt, 1);
            if (p < NCAND) cand[b * NCAND + p] = i;
        } else if (k == T) {
            int p = atomicAdd(&sh_eqcnt, 1);
            if (p < 64) eq[p] = i;
        }
    }
    __syncthreads();
    if (tid == 0) {
        int cg = sh_cntgt; if (cg > NCAND) cg = NCAND;
        int ec = sh_eqcnt; if (ec > 64) ec = 64;
        int need = NCAND - cg; if (need > ec) need = ec; if (need < 0) need = 0;
        for (int a = 1; a < ec; ++a) {           // ascending index
            int v = eq[a]; int j = a - 1;
            while (j >= 0 && eq[j] > v) { eq[j + 1] = eq[j]; --j; }
            eq[j + 1] = v;
        }
        for (int j = 0; j < need; ++j) cand[b * NCAND + cg + j] = eq[j];
    }
}

// ---------------------------------------------------------------------------
// Exact fp32 rescore of the 4096 candidate slots (round-1 SGEMM + gather).
// pc[4][NSLOT] partials over h-tiles.
// ---------------------------------------------------------------------------
#define KC 16
#define TILE 128
#define LDP (TILE + 4)

__global__ __launch_bounds__(256) void rescore_kernel(
    const float* __restrict__ x, const int* __restrict__ cand,
    const float* __restrict__ W1, const float* __restrict__ b1,
    const float* __restrict__ W2, float* __restrict__ pc)
{
    __shared__ float As[KC][LDP];
    __shared__ float Bs[KC][LDP];
    __shared__ int rowbase[TILE];

    const int tid = threadIdx.x;
    const int s0 = blockIdx.x * TILE;
    const int h0 = blockIdx.y * TILE;
    const int tx = tid & 15;
    const int ty = tid >> 4;
    const int lt = tid >> 2;
    const int lq = tid & 3;

    if (tid < TILE) {
        const int slot = s0 + tid;
        const int bat = slot >> 8;
        rowbase[tid] = bat * NN + (cand[slot] & (NN - 1));
    }
    __syncthreads();

    const float* Arow0 = x + (size_t)rowbase[lt] * DD;
    const float* Arow1 = x + (size_t)rowbase[lt + 64] * DD;
    const float* Brow0 = W1 + (size_t)(h0 + lt) * DD;
    const float* Brow1 = W1 + (size_t)(h0 + lt + 64) * DD;

    float acc[8][8];
#pragma unroll
    for (int i = 0; i < 8; ++i)
#pragma unroll
        for (int j = 0; j < 8; ++j) acc[i][j] = 0.0f;

    for (int kc = 0; kc < DD; kc += KC) {
        float4 a0 = *(const float4*)(Arow0 + kc + lq * 4);
        float4 a1 = *(const float4*)(Arow1 + kc + lq * 4);
        float4 w0 = *(const float4*)(Brow0 + kc + lq * 4);
        float4 w1 = *(const float4*)(Brow1 + kc + lq * 4);
        __syncthreads();
        As[lq * 4 + 0][lt] = a0.x; As[lq * 4 + 1][lt] = a0.y;
        As[lq * 4 + 2][lt] = a0.z; As[lq * 4 + 3][lt] = a0.w;
        As[lq * 4 + 0][lt + 64] = a1.x; As[lq * 4 + 1][lt + 64] = a1.y;
        As[lq * 4 + 2][lt + 64] = a1.z; As[lq * 4 + 3][lt + 64] = a1.w;
        Bs[lq * 4 + 0][lt] = w0.x; Bs[lq * 4 + 1][lt] = w0.y;
        Bs[lq * 4 + 2][lt] = w0.z; Bs[lq * 4 + 3][lt] = w0.w;
        Bs[lq * 4 + 0][lt + 64] = w1.x; Bs[lq * 4 + 1][lt + 64] = w1.y;
        Bs[lq * 4 + 2][lt + 64] = w1.z; Bs[lq * 4 + 3][lt + 64] = w1.w;
        __syncthreads();
#pragma unroll
        for (int kk = 0; kk < KC; ++kk) {
            float ra[8], rb[8];
            *(float4*)&ra[0] = *(const float4*)&As[kk][ty * 8];
            *(float4*)&ra[4] = *(const float4*)&As[kk][ty * 8 + 4];
            *(float4*)&rb[0] = *(const float4*)&Bs[kk][tx * 8];
            *(float4*)&rb[4] = *(const float4*)&Bs[kk][tx * 8 + 4];
#pragma unroll
            for (int i = 0; i < 8; ++i)
#pragma unroll
                for (int j = 0; j < 8; ++j)
                    acc[i][j] = fmaf(ra[i], rb[j], acc[i][j]);
        }
    }

    float s[8];
#pragma unroll
    for (int i = 0; i < 8; ++i) s[i] = 0.0f;
#pragma unroll
    for (int j = 0; j < 8; ++j) {
        const int h = h0 + tx * 8 + j;
        const float bias = b1[h];
        const float w2v = W2[h];
#pragma unroll
        for (int i = 0; i < 8; ++i) {
            float u = acc[i][j] + bias;
            float g = 0.5f * u * (1.0f + erff(u * 0.70710678118654752440f));
            s[i] = fmaf(g, w2v, s[i]);
        }
    }
#pragma unroll
    for (int i = 0; i < 8; ++i) {
#pragma unroll
        for (int off = 8; off > 0; off >>= 1)
            s[i] += __shfl_down(s[i], off, 16);
    }
    if (tx == 0) {
#pragma unroll
        for (int i = 0; i < 8; ++i)
            pc[(size_t)blockIdx.y * NSLOT + s0 + ty * 8 + i] = s[i];
    }
}

// ---------------------------------------------------------------------------
// Final exact top-200 per batch over 256 candidates (value desc, tie -> lower
// token index).  One block/batch, thread t owns candidate slot t.
// ---------------------------------------------------------------------------
__global__ __launch_bounds__(256) void final_topk(
    const float* __restrict__ pc, const int* __restrict__ cand,
    int* __restrict__ topk)
{
    __shared__ float wv[4];
    __shared__ int wt[4], wsl[4];
    __shared__ int win_slot;
    const int b = blockIdx.x, tid = threadIdx.x;
    const int slot = b * NCAND + tid;
    float es = pc[slot] + pc[NSLOT + slot] + pc[2 * NSLOT + slot] + pc[3 * NSLOT + slot];
    const int tok = cand[slot];

    for (int k = 0; k < KSEL; ++k) {
        float v = es; int t = tok; int s = tid;
#pragma unroll
        for (int off = 32; off > 0; off >>= 1) {
            float ov = __shfl_down(v, off, 64);
            int ot = __shfl_down(t, off, 64);
            int os = __shfl_down(s, off, 64);
            if (ov > v || (ov == v && ot < t)) { v = ov; t = ot; s = os; }
        }
        if ((tid & 63) == 0) { int wd = tid >> 6; wv[wd] = v; wt[wd] = t; wsl[wd] = s; }
        __syncthreads();
        if (tid == 0) {
            float xv = wv[0]; int xt = wt[0], xs = wsl[0];
#pragma unroll
            for (int g = 1; g < 4; ++g)
                if (wv[g] > xv || (wv[g] == xv && wt[g] < xt)) { xv = wv[g]; xt = wt[g]; xs = wsl[g]; }
            topk[b * KSEL + k] = xt;
            win_slot = xs;
        }
        __syncthreads();
        if (tid == win_slot) es = -INFINITY;
        __syncthreads();
    }
}

// ---------------------------------------------------------------------------
// Projection via bf16 MFMA: out[r][o] = x[row(r)] . Wp[o] + bp[o], fp32 out.
// A: gathered fp32 rows converted in staging; B: Wpb (bf16).
// ---------------------------------------------------------------------------
__global__ __launch_bounds__(256) void proj_mfma(
    const float* __restrict__ x, const int* __restrict__ topk,
    const unsigned short* __restrict__ Wpb, const float* __restrict__ bp,
    float* __restrict__ out)
{
    __shared__ __align__(16) unsigned short As[128 * LDSA];
    __shared__ __align__(16) unsigned short Bs[128 * LDSA];
    __shared__ int rowbase[128];

    const int tid = threadIdx.x;
    const int r0 = blockIdx.x * 128;
    const int o0 = blockIdx.y * 128;
    const int lane = tid & 63;
    const int w = tid >> 6;
    const int wr = w & 1, wc = w >> 1;
    const int l15 = lane & 15, q = lane >> 4;
    const int sr = tid >> 1;
    const int sc = tid & 1;

    if (tid < 128) {
        const int r = r0 + tid;
        const int bat = r / KSEL;
        rowbase[tid] = bat * NN + (topk[r] & (NN - 1));
    }
    __syncthreads();

    const float* xrow = x + (size_t)rowbase[sr] * DD + sc * 16;
    const unsigned short* wrow = Wpb + (size_t)(o0 + sr) * DD + sc * 16;

    floatx4 acc[4][4];
#pragma unroll
    for (int mi = 0; mi < 4; ++mi)
#pragma unroll
        for (int ni = 0; ni < 4; ++ni) acc[mi][ni] = (floatx4){0.f, 0.f, 0.f, 0.f};

    for (int kc = 0; kc < DD; kc += BKA) {
        float4 a0 = *(const float4*)(xrow + kc);
        float4 a1 = *(const float4*)(xrow + kc + 4);
        float4 a2 = *(const float4*)(xrow + kc + 8);
        float4 a3 = *(const float4*)(xrow + kc + 12);
        uint4 bv0 = *(const uint4*)(wrow + kc);
        uint4 bv1 = *(const uint4*)(wrow + kc + 8);
        __syncthreads();
        uint4 ua0 = make_uint4(pk2(a0.x, a0.y), pk2(a0.z, a0.w), pk2(a1.x, a1.y), pk2(a1.z, a1.w));
        uint4 ua1 = make_uint4(pk2(a2.x, a2.y), pk2(a2.z, a2.w), pk2(a3.x, a3.y), pk2(a3.z, a3.w));
        *(uint4*)&As[sr * LDSA + sc * 16] = ua0;
        *(uint4*)&As[sr * LDSA + sc * 16 + 8] = ua1;
        *(uint4*)&Bs[sr * LDSA + sc * 16] = bv0;
        *(uint4*)&Bs[sr * LDSA + sc * 16 + 8] = bv1;
        __syncthreads();
        bf16x8 af[4], bf[4];
#pragma unroll
        for (int mi = 0; mi < 4; ++mi)
            af[mi] = *(const bf16x8*)&As[(wr * 64 + mi * 16 + l15) * LDSA + q * 8];
#pragma unroll
        for (int ni = 0; ni < 4; ++ni)
            bf[ni] = *(const bf16x8*)&Bs[(wc * 64 + ni * 16 + l15) * LDSA + q * 8];
#pragma unroll
        for (int mi = 0; mi < 4; ++mi)
#pragma unroll
            for (int ni = 0; ni < 4; ++ni)
                acc[mi][ni] = __builtin_amdgcn_mfma_f32_16x16x32_bf16(af[mi], bf[ni], acc[mi][ni], 0, 0, 0);
    }

    float bpv[4];
#pragma unroll
    for (int ni = 0; ni < 4; ++ni) bpv[ni] = bp[o0 + wc * 64 + ni * 16 + l15];
#pragma unroll
    for (int mi = 0; mi < 4; ++mi)
#pragma unroll
        for (int r = 0; r < 4; ++r) {
            const size_t row = (size_t)(r0 + wr * 64 + mi * 16 + q * 4 + r) * OO;
#pragma unroll
            for (int ni = 0; ni < 4; ++ni)
                out[row + o0 + wc * 64 + ni * 16 + l15] = acc[mi][ni][r] + bpv[ni];
        }
}

// ---------------------------------------------------------------------------
extern "C" void kernel_launch(void* const* d_in, const int* in_sizes, int n_in,
                              void* d_out, int out_size, void* d_ws, size_t ws_size,
                              hipStream_t stream) {
    const float* x  = (const float*)d_in[0];
    const float* W1 = (const float*)d_in[1];
    const float* b1 = (const float*)d_in[2];
    const float* W2 = (const float*)d_in[3];
    // d_in[4] = b2: uniform shift -> irrelevant for top-k, scores not output
    const float* Wp = (const float*)d_in[5];
    const float* bp = (const float*)d_in[6];
    float* out = (float*)d_out;

    char* ws = (char*)d_ws;
    float* partials       = (float*)(ws);                        // 4*NT*4   = 1 MB
    float* pc             = (float*)(ws + 1048576);              // 4*NSLOT*4= 64 KB
    int*   cand           = (int*)  (ws + 1114112);              // 16 KB
    int*   topk           = (int*)  (ws + 1130496);              // 12.8 KB
    unsigned short* W1b   = (unsigned short*)(ws + 1143808);     // 1 MB
    unsigned short* Wpb   = (unsigned short*)(ws + 2192384);     // 8 MB
    // total ~10.6 MB

    convert_bf16<<<dim3((HH * DD / 8) / 256), 256, 0, stream>>>(W1, W1b, HH * DD / 8);
    convert_bf16<<<dim3((OO * DD / 8) / 256), 256, 0, stream>>>(Wp, Wpb, OO * DD / 8);

    score_mfma<<<dim3(HH / 128, NT / 128), 256, 0, stream>>>(x, W1b, b1, W2, partials);

    cand_select<<<dim3(BB), 256, 0, stream>>>(partials, cand);

    rescore_kernel<<<dim3(NSLOT / TILE, HH / TILE), 256, 0, stream>>>(x, cand, W1, b1, W2, pc);

    final_topk<<<dim3(BB), 256, 0, stream>>>(pc, cand, topk);

    proj_mfma<<<dim3((BB * KSEL) / 128, OO / 128), 256, 0, stream>>>(x, topk, Wpb, bp, out);
}

// Round 3
// 796.753 us; speedup vs baseline: 2.6072x; 1.5033x over previous
//
#include <hip/hip_runtime.h>
#include <cmath>

#define BB 16
#define NN 4096
#define DD 1024
#define HH 512
#define OO 4096
#define KSEL 200
#define NCAND 256
#define NT (BB * NN)          // 65536
#define NSLOT (BB * NCAND)    // 4096

typedef __bf16 bf16x8 __attribute__((ext_vector_type(8)));
typedef float floatx4 __attribute__((ext_vector_type(4)));

__device__ __forceinline__ unsigned short f2b(float f) {
    union { float f; unsigned u; } v; v.f = f;
    unsigned r = v.u + 0x7fffu + ((v.u >> 16) & 1u);   // RNE
    return (unsigned short)(r >> 16);
}
__device__ __forceinline__ unsigned pk2(float lo, float hi) {
    return (unsigned)f2b(lo) | ((unsigned)f2b(hi) << 16);
}

// async global->LDS, 16 B per lane.  LDS dest = wave-uniform base + lane*16.
__device__ __forceinline__ void gl16(const void* g, void* l) {
    __builtin_amdgcn_global_load_lds(
        (const __attribute__((address_space(1))) unsigned int*)g,
        (__attribute__((address_space(3))) unsigned int*)l, 16, 0, 0);
}

// ---------------------------------------------------------------------------
// fp32 -> bf16 converter (x, W1, Wp), 8 elems/thread
// ---------------------------------------------------------------------------
__global__ __launch_bounds__(256) void convert_bf16(
    const float* __restrict__ src, unsigned short* __restrict__ dst, int n8)
{
    int i = blockIdx.x * 256 + threadIdx.x;
    if (i >= n8) return;
    float4 a = ((const float4*)src)[2 * i];
    float4 b = ((const float4*)src)[2 * i + 1];
    uint4 o = make_uint4(pk2(a.x, a.y), pk2(a.z, a.w), pk2(b.x, b.y), pk2(b.z, b.w));
    ((uint4*)dst)[i] = o;
}

// ---------------------------------------------------------------------------
// Approx scores, m97-style: A = xb[128 tok], B = W1b[128 h], BK=64,
// global_load_lds staging with XOR-swizzled layout (swizzle applied to the
// GLOBAL fetch column so the forced lane-contiguous LDS deposit lands
// swizzled; frag reads then see <=2-way bank alias).
// grid = (HH/128 = 4, NT/128 = 512).  partials[4][NT].
// ---------------------------------------------------------------------------
#define BK 64

__global__ __launch_bounds__(256) void score_mfma(
    const unsigned short* __restrict__ xb, const unsigned short* __restrict__ W1b,
    const float* __restrict__ b1, const float* __restrict__ W2,
    float* __restrict__ partials)
{
    __shared__ __align__(16) unsigned short As[128 * BK];
    __shared__ __align__(16) unsigned short Bs[128 * BK];
    __shared__ float red[2][128];

    const int tid = threadIdx.x;
    const int h0 = blockIdx.x * 128;
    const int t0 = blockIdx.y * 128;
    const int lane = tid & 63;
    const int w = tid >> 6;
    const int wr = w & 1, wc = w >> 1;
    const int l15 = lane & 15, q = lane >> 4;

    // staging geometry: transfer t = i*256 + tid; row = t/8, blk = t%8
    const int srow = tid >> 3;                 // 0..31 (+ i*32)
    const int cb = (tid & 7) ^ (srow & 7);     // swizzled global col-block
    const unsigned short* pA[4];
    const unsigned short* pB[4];
#pragma unroll
    for (int i = 0; i < 4; ++i) {
        pA[i] = xb  + (size_t)(t0 + i * 32 + srow) * DD + cb * 8;
        pB[i] = W1b + (size_t)(h0 + i * 32 + srow) * DD + cb * 8;
    }

    floatx4 acc[4][4];
#pragma unroll
    for (int mi = 0; mi < 4; ++mi)
#pragma unroll
        for (int ni = 0; ni < 4; ++ni) acc[mi][ni] = (floatx4){0.f, 0.f, 0.f, 0.f};

    for (int kc = 0; kc < DD; kc += BK) {
        __syncthreads();   // previous tile fully consumed
#pragma unroll
        for (int i = 0; i < 4; ++i) {
            gl16(pA[i] + kc, &As[(i * 256 + w * 64) * 8]);
            gl16(pB[i] + kc, &Bs[(i * 256 + w * 64) * 8]);
        }
        __syncthreads();   // DMA drained (vmcnt(0) before barrier)
#pragma unroll
        for (int kk = 0; kk < BK; kk += 32) {
            const int kb = kk >> 3;
            bf16x8 af[4], bf[4];
#pragma unroll
            for (int mi = 0; mi < 4; ++mi) {
                const int r = wr * 64 + mi * 16 + l15;
                af[mi] = *(const bf16x8*)&As[r * BK + (((kb + q) ^ (r & 7)) << 3)];
            }
#pragma unroll
            for (int ni = 0; ni < 4; ++ni) {
                const int r = wc * 64 + ni * 16 + l15;
                bf[ni] = *(const bf16x8*)&Bs[r * BK + (((kb + q) ^ (r & 7)) << 3)];
            }
#pragma unroll
            for (int mi = 0; mi < 4; ++mi)
#pragma unroll
                for (int ni = 0; ni < 4; ++ni)
                    acc[mi][ni] = __builtin_amdgcn_mfma_f32_16x16x32_bf16(af[mi], bf[ni], acc[mi][ni], 0, 0, 0);
        }
    }

    // epilogue: gelu + W2-dot over 128 h, reduce cols -> tokens
    float s[4][4];
#pragma unroll
    for (int mi = 0; mi < 4; ++mi)
#pragma unroll
        for (int r = 0; r < 4; ++r) s[mi][r] = 0.f;
#pragma unroll
    for (int ni = 0; ni < 4; ++ni) {
        const int n = h0 + wc * 64 + ni * 16 + l15;
        const float bias = b1[n];
        const float w2v = W2[n];
#pragma unroll
        for (int mi = 0; mi < 4; ++mi)
#pragma unroll
            for (int r = 0; r < 4; ++r) {
                float u = acc[mi][ni][r] + bias;
                float g = 0.5f * u * (1.0f + erff(u * 0.70710678118654752440f));
                s[mi][r] = fmaf(g, w2v, s[mi][r]);
            }
    }
#pragma unroll
    for (int mi = 0; mi < 4; ++mi)
#pragma unroll
        for (int r = 0; r < 4; ++r) {
#pragma unroll
            for (int off = 1; off < 16; off <<= 1)
                s[mi][r] += __shfl_xor(s[mi][r], off, 64);
        }
    __syncthreads();
    if (l15 == 0) {
#pragma unroll
        for (int mi = 0; mi < 4; ++mi)
#pragma unroll
            for (int r = 0; r < 4; ++r)
                red[wc][wr * 64 + mi * 16 + q * 4 + r] = s[mi][r];
    }
    __syncthreads();
    if (tid < 128)
        partials[(size_t)blockIdx.x * NT + t0 + tid] = red[0][tid] + red[1][tid];
}

// ---------------------------------------------------------------------------
// Per-batch candidate select: radix-select 256th-largest approx score,
// compact all > T + equal-T.  Deterministic SET (order immaterial).
// ---------------------------------------------------------------------------
__global__ __launch_bounds__(256) void cand_select(
    const float* __restrict__ partials, int* __restrict__ cand)
{
    __shared__ unsigned uk[NN];
    __shared__ int hist[256];
    __shared__ int eq[64];
    __shared__ int sh_pref, sh_rk, sh_cntgt, sh_eqcnt;
    const int b = blockIdx.x, tid = threadIdx.x;

    for (int i = tid; i < NN; i += 256) {
        const int t = b * NN + i;
        float v = partials[t] + partials[NT + t] + partials[2 * NT + t] + partials[3 * NT + t];
        union { float f; unsigned u; } c; c.f = v;
        uk[i] = (c.u & 0x80000000u) ? ~c.u : (c.u | 0x80000000u);
    }
    if (tid == 0) { sh_pref = 0; sh_rk = NCAND; }
    __syncthreads();

    for (int sh = 24; sh >= 0; sh -= 8) {
        hist[tid] = 0;
        __syncthreads();
        const unsigned pref = (unsigned)sh_pref;
        for (int i = tid; i < NN; i += 256) {
            unsigned k = uk[i];
            bool match = (sh == 24) || (((k ^ pref) >> (sh + 8)) == 0);
            if (match) atomicAdd(&hist[(k >> sh) & 255], 1);
        }
        __syncthreads();
        if (tid == 0) {
            int rk = sh_rk, cum = 0;
            for (int bin = 255; bin >= 0; --bin) {
                int c = hist[bin];
                if (cum + c >= rk) { sh_pref = (int)(pref | ((unsigned)bin << sh)); sh_rk = rk - cum; break; }
                cum += c;
            }
        }
        __syncthreads();
    }
    const unsigned T = (unsigned)sh_pref;
    if (tid == 0) { sh_cntgt = 0; sh_eqcnt = 0; }
    cand[b * NCAND + tid] = 0;
    __syncthreads();
    for (int i = tid; i < NN; i += 256) {
        unsigned k = uk[i];
        if (k > T) {
            int p = atomicAdd(&sh_cntgt, 1);
            if (p < NCAND) cand[b * NCAND + p] = i;
        } else if (k == T) {
            int p = atomicAdd(&sh_eqcnt, 1);
            if (p < 64) eq[p] = i;
        }
    }
    __syncthreads();
    if (tid == 0) {
        int cg = sh_cntgt; if (cg > NCAND) cg = NCAND;
        int ec = sh_eqcnt; if (ec > 64) ec = 64;
        int need = NCAND - cg; if (need > ec) need = ec; if (need < 0) need = 0;
        for (int a = 1; a < ec; ++a) {
            int v = eq[a]; int j = a - 1;
            while (j >= 0 && eq[j] > v) { eq[j + 1] = eq[j]; --j; }
            eq[j + 1] = v;
        }
        for (int j = 0; j < need; ++j) cand[b * NCAND + cg + j] = eq[j];
    }
}

// ---------------------------------------------------------------------------
// Exact fp32 rescore, 64x64 tiles -> grid (64, 8) = 512 blocks.
// pc[8][NSLOT] partials over h-tiles of 64 (gelu needs full K -> h split only).
// ---------------------------------------------------------------------------
#define RT 64
#define RLDP 68   // 68*4 bytes, multiple of 16 -> aligned float4 rows

__global__ __launch_bounds__(256) void rescore_kernel(
    const float* __restrict__ x, const int* __restrict__ cand,
    const float* __restrict__ W1, const float* __restrict__ b1,
    const float* __restrict__ W2, float* __restrict__ pc)
{
    __shared__ float As[16][RLDP];
    __shared__ float Bs[16][RLDP];
    __shared__ int rowbase[RT];

    const int tid = threadIdx.x;
    const int s0 = blockIdx.x * RT;
    const int h0 = blockIdx.y * RT;
    const int tx = tid & 15;
    const int ty = tid >> 4;
    const int lr = tid >> 2;
    const int lq = tid & 3;

    if (tid < RT) {
        const int slot = s0 + tid;
        rowbase[tid] = (slot >> 8) * NN + (cand[slot] & (NN - 1));
    }
    __syncthreads();

    const float* Arow = x + (size_t)rowbase[lr] * DD;
    const float* Brow = W1 + (size_t)(h0 + lr) * DD;

    float acc[4][4];
#pragma unroll
    for (int i = 0; i < 4; ++i)
#pragma unroll
        for (int j = 0; j < 4; ++j) acc[i][j] = 0.0f;

    for (int kc = 0; kc < DD; kc += 16) {
        float4 a = *(const float4*)(Arow + kc + lq * 4);
        float4 wv = *(const float4*)(Brow + kc + lq * 4);
        __syncthreads();
        As[lq * 4 + 0][lr] = a.x; As[lq * 4 + 1][lr] = a.y;
        As[lq * 4 + 2][lr] = a.z; As[lq * 4 + 3][lr] = a.w;
        Bs[lq * 4 + 0][lr] = wv.x; Bs[lq * 4 + 1][lr] = wv.y;
        Bs[lq * 4 + 2][lr] = wv.z; Bs[lq * 4 + 3][lr] = wv.w;
        __syncthreads();
#pragma unroll
        for (int kk = 0; kk < 16; ++kk) {
            float ra[4], rb[4];
            *(float4*)&ra[0] = *(const float4*)&As[kk][ty * 4];
            *(float4*)&rb[0] = *(const float4*)&Bs[kk][tx * 4];
#pragma unroll
            for (int i = 0; i < 4; ++i)
#pragma unroll
                for (int j = 0; j < 4; ++j)
                    acc[i][j] = fmaf(ra[i], rb[j], acc[i][j]);
        }
    }

    float s[4];
#pragma unroll
    for (int i = 0; i < 4; ++i) s[i] = 0.0f;
#pragma unroll
    for (int j = 0; j < 4; ++j) {
        const int h = h0 + tx * 4 + j;
        const float bias = b1[h];
        const float w2v = W2[h];
#pragma unroll
        for (int i = 0; i < 4; ++i) {
            float u = acc[i][j] + bias;
            float g = 0.5f * u * (1.0f + erff(u * 0.70710678118654752440f));
            s[i] = fmaf(g, w2v, s[i]);
        }
    }
#pragma unroll
    for (int i = 0; i < 4; ++i) {
#pragma unroll
        for (int off = 8; off > 0; off >>= 1)
            s[i] += __shfl_down(s[i], off, 16);
    }
    if (tx == 0) {
#pragma unroll
        for (int i = 0; i < 4; ++i)
            pc[(size_t)blockIdx.y * NSLOT + s0 + ty * 4 + i] = s[i];
    }
}

// ---------------------------------------------------------------------------
// Final exact top-200: bitonic sort of 256 packed keys per batch.
// key = mono(score)<<12 | (4095 - token)  -> desc sort == score desc, tok asc.
// ---------------------------------------------------------------------------
__global__ __launch_bounds__(256) void final_topk(
    const float* __restrict__ pc, const int* __restrict__ cand,
    int* __restrict__ topk)
{
    __shared__ unsigned long long keys[NCAND];
    const int b = blockIdx.x, tid = threadIdx.x;
    const int slot = b * NCAND + tid;
    float es = 0.f;
#pragma unroll
    for (int g = 0; g < 8; ++g) es += pc[(size_t)g * NSLOT + slot];
    const int tok = cand[slot];
    union { float f; unsigned u; } c; c.f = es;
    unsigned mono = (c.u & 0x80000000u) ? ~c.u : (c.u | 0x80000000u);
    keys[tid] = ((unsigned long long)mono << 12) | (unsigned)(4095 - tok);
    __syncthreads();

    for (int k = 2; k <= NCAND; k <<= 1) {
        for (int j = k >> 1; j > 0; j >>= 1) {
            const int p = tid ^ j;
            const unsigned long long a = keys[tid];
            const unsigned long long o = keys[p];
            const unsigned long long hi = a > o ? a : o;
            const unsigned long long lo = a > o ? o : a;
            const unsigned long long nv = ((tid < p) == ((tid & k) == 0)) ? hi : lo;
            __syncthreads();
            keys[tid] = nv;
            __syncthreads();
        }
    }
    if (tid < KSEL) topk[b * KSEL + tid] = 4095 - (int)(keys[tid] & 4095u);
}

// ---------------------------------------------------------------------------
// Projection, m97-style with gathered A rows (xb) and Wpb, fp32 out + bp.
// ---------------------------------------------------------------------------
__global__ __launch_bounds__(256) void proj_mfma(
    const unsigned short* __restrict__ xb, const int* __restrict__ topk,
    const unsigned short* __restrict__ Wpb, const float* __restrict__ bp,
    float* __restrict__ out)
{
    __shared__ __align__(16) unsigned short As[128 * BK];
    __shared__ __align__(16) unsigned short Bs[128 * BK];
    __shared__ int rowbase[128];

    const int tid = threadIdx.x;
    const int r0 = blockIdx.x * 128;
    const int o0 = blockIdx.y * 128;
    const int lane = tid & 63;
    const int w = tid >> 6;
    const int wr = w & 1, wc = w >> 1;
    const int l15 = lane & 15, q = lane >> 4;

    if (tid < 128) {
        const int r = r0 + tid;
        rowbase[tid] = (r / KSEL) * NN + (topk[r] & (NN - 1));
    }
    __syncthreads();

    const int srow = tid >> 3;
    const int cb = (tid & 7) ^ (srow & 7);
    const unsigned short* pA[4];
    const unsigned short* pB[4];
#pragma unroll
    for (int i = 0; i < 4; ++i) {
        pA[i] = xb  + (size_t)rowbase[i * 32 + srow] * DD + cb * 8;
        pB[i] = Wpb + (size_t)(o0 + i * 32 + srow) * DD + cb * 8;
    }

    floatx4 acc[4][4];
#pragma unroll
    for (int mi = 0; mi < 4; ++mi)
#pragma unroll
        for (int ni = 0; ni < 4; ++ni) acc[mi][ni] = (floatx4){0.f, 0.f, 0.f, 0.f};

    for (int kc = 0; kc < DD; kc += BK) {
        __syncthreads();
#pragma unroll
        for (int i = 0; i < 4; ++i) {
            gl16(pA[i] + kc, &As[(i * 256 + w * 64) * 8]);
            gl16(pB[i] + kc, &Bs[(i * 256 + w * 64) * 8]);
        }
        __syncthreads();
#pragma unroll
        for (int kk = 0; kk < BK; kk += 32) {
            const int kb = kk >> 3;
            bf16x8 af[4], bf[4];
#pragma unroll
            for (int mi = 0; mi < 4; ++mi) {
                const int r = wr * 64 + mi * 16 + l15;
                af[mi] = *(const bf16x8*)&As[r * BK + (((kb + q) ^ (r & 7)) << 3)];
            }
#pragma unroll
            for (int ni = 0; ni < 4; ++ni) {
                const int r = wc * 64 + ni * 16 + l15;
                bf[ni] = *(const bf16x8*)&Bs[r * BK + (((kb + q) ^ (r & 7)) << 3)];
            }
#pragma unroll
            for (int mi = 0; mi < 4; ++mi)
#pragma unroll
                for (int ni = 0; ni < 4; ++ni)
                    acc[mi][ni] = __builtin_amdgcn_mfma_f32_16x16x32_bf16(af[mi], bf[ni], acc[mi][ni], 0, 0, 0);
        }
    }

    float bpv[4];
#pragma unroll
    for (int ni = 0; ni < 4; ++ni) bpv[ni] = bp[o0 + wc * 64 + ni * 16 + l15];
#pragma unroll
    for (int mi = 0; mi < 4; ++mi)
#pragma unroll
        for (int r = 0; r < 4; ++r) {
            const size_t row = (size_t)(r0 + wr * 64 + mi * 16 + q * 4 + r) * OO;
#pragma unroll
            for (int ni = 0; ni < 4; ++ni)
                out[row + o0 + wc * 64 + ni * 16 + l15] = acc[mi][ni][r] + bpv[ni];
        }
}

// ---------------------------------------------------------------------------
extern "C" void kernel_launch(void* const* d_in, const int* in_sizes, int n_in,
                              void* d_out, int out_size, void* d_ws, size_t ws_size,
                              hipStream_t stream) {
    const float* x  = (const float*)d_in[0];
    const float* W1 = (const float*)d_in[1];
    const float* b1 = (const float*)d_in[2];
    const float* W2 = (const float*)d_in[3];
    // d_in[4] = b2: uniform shift -> irrelevant for top-k, scores not output
    const float* Wp = (const float*)d_in[5];
    const float* bp = (const float*)d_in[6];
    float* out = (float*)d_out;

    char* ws = (char*)d_ws;
    unsigned short* xb  = (unsigned short*)(ws);                   // 128 MB
    unsigned short* W1b = (unsigned short*)(ws + 134217728);       // 1 MB
    unsigned short* Wpb = (unsigned short*)(ws + 135266304);       // 8 MB
    float* partials     = (float*)(ws + 143654912);                // 1 MB
    float* pc           = (float*)(ws + 144703488);                // 128 KB
    int*   cand         = (int*)  (ws + 144834560);                // 16 KB
    int*   topk         = (int*)  (ws + 144850944);                // 12.8 KB
    // total ~144.9 MB

    convert_bf16<<<dim3((NT * DD / 8) / 256), 256, 0, stream>>>(x, xb, NT * DD / 8);
    convert_bf16<<<dim3((HH * DD / 8) / 256), 256, 0, stream>>>(W1, W1b, HH * DD / 8);
    convert_bf16<<<dim3((OO * DD / 8) / 256), 256, 0, stream>>>(Wp, Wpb, OO * DD / 8);

    score_mfma<<<dim3(HH / 128, NT / 128), 256, 0, stream>>>(xb, W1b, b1, W2, partials);

    cand_select<<<dim3(BB), 256, 0, stream>>>(partials, cand);

    rescore_kernel<<<dim3(NSLOT / RT, HH / RT), 256, 0, stream>>>(x, cand, W1, b1, W2, pc);

    final_topk<<<dim3(BB), 256, 0, stream>>>(pc, cand, topk);

    proj_mfma<<<dim3((BB * KSEL) / 128, OO / 128), 256, 0, stream>>>(xb, topk, Wpb, bp, out);
}